// Round 9
// baseline (30.699 us; speedup 1.0000x reference)
//
#include <hip/hip_runtime.h>
#include <cfloat>

#define NS 7
#define NC 256
#define NH 64
#define NW 64
#define NR 128
#define SPAD 66   // stripe row stride (>= 65 for safe masked read at w=64)

// Wave = (channel, 4 rois). Lanes: half = row-parity, w2 = w-pair (full row).
// Phase 1: per h-bin column-max, float2 loads = 2 rows x 64 w per instr,
//   7-bin volleys, row clamped (duplicate reads, no masks), permlane32 fold.
// Phase 2: wave-private LDS stripe [7][64], K+1 reads/bin (sp in {K,K+1}).
// Grid 2048 = 8 blocks/CU (all resident); blocks on a CU share the channel.
__global__ __launch_bounds__(256, 8) void roi_pool_kernel(
    const float* __restrict__ f,
    const int* __restrict__ rois,
    float* __restrict__ out)
{
    __shared__ float stripe_all[4][NS][SPAD];   // 7.4 KB

    const int tid  = threadIdx.x;
    const int lane = tid & 63;
    const int wid  = tid >> 6;
    float (*stripe)[SPAD] = stripe_all[wid];

    const int c  = blockIdx.x & 255;    // same-c blocks land on same CU
    const int rg = blockIdx.x >> 8;     // 0..7
    const int r0 = rg * 16 + wid * 4;

    const char* fcb = (const char*)(f + (size_t)c * (NH * NW));

    const int w2    = lane & 31;
    const int halfb = (lane >> 5) << 8;   // row-parity in bytes (0 or 256)
    const int woff  = w2 * 8;             // byte offset within a row

    // phase-2 lane decomposition (hoisted)
    const int bl = lane < NS * NS ? lane : NS * NS - 1;
    const int bi = bl / NS;
    const int bj = bl - bi * NS;

    for (int rr = 0; rr < 4; ++rr) {
        const int r  = r0 + rr;
        const int x1 = __builtin_amdgcn_readfirstlane(rois[4 * r + 0]);
        const int y1 = __builtin_amdgcn_readfirstlane(rois[4 * r + 1]);
        const int x2 = __builtin_amdgcn_readfirstlane(rois[4 * r + 2]);
        const int y2 = __builtin_amdgcn_readfirstlane(rois[4 * r + 3]);
        const int Lh = x2 - x1 + 1;
        const int Lw = y2 - y1 + 1;

        // scalar per-bin row bounds (bytes)
        int hsb[NS], helimb[NS];
        int maxrows = 0;
        #pragma unroll
        for (int i = 0; i < NS; ++i) {
            int hs = x1 + (i * Lh) / NS;
            int he = x1 + ((i + 1) * Lh + NS - 1) / NS;
            hsb[i]    = hs << 8;
            helimb[i] = (he - 1) << 8;
            maxrows   = max(maxrows, he - hs);
        }
        const int K2 = (maxrows + 1) >> 1;   // row-pair volleys, wave-uniform

        float2 acc[NS];
        #pragma unroll
        for (int i = 0; i < NS; ++i) acc[i] = make_float2(-FLT_MAX, -FLT_MAX);

        for (int k = 0; k < K2; ++k) {
            const int kb = k << 9;           // 2 rows per volley
            #pragma unroll
            for (int i = 0; i < NS; ++i) {   // 7 independent coalesced loads
                int rb = min(hsb[i] + kb + halfb, helimb[i]);  // clamp = dup read
                float2 v = *(const float2*)(fcb + rb + woff);
                acc[i].x = fmaxf(acc[i].x, v.x);
                acc[i].y = fmaxf(acc[i].y, v.y);
            }
        }

        // fold row-parity halves (lanes 0..31 <- max with lanes 32..63)
        #pragma unroll
        for (int i = 0; i < NS; ++i) {
            float ax = acc[i].x, bx = acc[i].x;
            float ay = acc[i].y, by = acc[i].y;
            asm("v_permlane32_swap_b32 %0, %1" : "+v"(ax), "+v"(bx));
            asm("v_permlane32_swap_b32 %0, %1" : "+v"(ay), "+v"(by));
            float2 mv = make_float2(fmaxf(ax, bx), fmaxf(ay, by));
            if (lane < 32)
                *(float2*)&stripe[i][2 * w2] = mv;
        }

        // phase 2: per-bin w-window max over stripe (sp in {K, K+1})
        {
            const int Kc  = (Lw + NS - 1) / NS;            // wave-uniform
            const int wsj = y1 + (bj * Lw) / NS;            // per-lane
            const int wej = y1 + ((bj + 1) * Lw + NS - 1) / NS;
            const int spj = wej - wsj;

            float m = -FLT_MAX;
            for (int k = 0; k <= Kc; ++k) {                 // scalar loop
                float v = stripe[bi][wsj + k];              // index <= 64 safe
                m = fmaxf(m, k < spj ? v : -FLT_MAX);
            }
            if (lane < NS * NS)
                out[((size_t)r * NC + c) * (NS * NS) + lane] = m;
        }
    }
}

extern "C" void kernel_launch(void* const* d_in, const int* in_sizes, int n_in,
                              void* d_out, int out_size, void* d_ws, size_t ws_size,
                              hipStream_t stream)
{
    const float* feature_map = (const float*)d_in[0];
    const int*   rois        = (const int*)d_in[1];
    float*       out         = (float*)d_out;

    const int grid  = 8 * 256;   // rg * c : 2048 blocks, all resident
    const int block = 256;

    roi_pool_kernel<<<grid, block, 0, stream>>>(feature_map, rois, out);
}